// Round 4
// baseline (4263.159 us; speedup 1.0000x reference)
//
#include <hip/hip_runtime.h>
#include <hip/hip_bf16.h>

#define THREADS 1024
#define NWAVE (THREADS / 64)

// One block per cloud, 16 waves (4/SIMD). __launch_bounds__(1024, 2) sets
// min-waves-per-EU=2 -> 256-VGPR budget, so the 80-float per-thread state
// (coords + running dist at NPT=20) stays in architectural VGPRs with no
// AGPR shuffling (round-3 killer: VGPR_Count=64 + accvgpr moves).
//
// Per iteration (ONE barrier):
//   distance + min-update + local argmax -> pack (distbits<<32)|~idx u64
//   key -> 6-round wave butterfly max -> lane0 writes partial to LDS
//   (parity buffer) -> barrier -> all threads max-scan 16 keys ->
//   readfirstlane winner idx -> uniform scalar load of winner coords.
// Key ordering: dists >= 0 so float bits are monotone as unsigned;
// lo = ~idx makes ties pick the SMALLEST index (np.argmax semantics).
template<int NPT>
__global__ __launch_bounds__(THREADS, 2)
void fps_kernel(const float* __restrict__ C, int n_pts, int m,
                int* __restrict__ idx_out) {
    const int b = blockIdx.x;
    const int t = threadIdx.x;
    const float* __restrict__ P = C + (size_t)b * n_pts * 3;

    float px[NPT], py[NPT], pz[NPT], dist[NPT];
#pragma unroll
    for (int j = 0; j < NPT; ++j) {
        int g = t + j * THREADS;
        if (g < n_pts) {
            px[j] = P[3 * g + 0];
            py[j] = P[3 * g + 1];
            pz[j] = P[3 * g + 2];
            dist[j] = 1e10f;
        } else {
            px[j] = 0.f; py[j] = 0.f; pz[j] = 0.f;
            dist[j] = -1.0f;   // sentinel: never wins (real dists >= 0)
        }
    }

    __shared__ unsigned long long s_p[2][NWAVE];

    if (t == 0) idx_out[(size_t)b * m] = 0;   // first index is always 0

    // initial center = point 0 (uniform -> scalar load)
    float lx = P[0], ly = P[1], lz = P[2];

    const int wid = t >> 6;

    for (int it = 1; it < m; ++it) {
        const int par = it & 1;
        float bv = -2.0f;
        int   bj = 0;
        // distance + min update + local argmax; ascending j with strict >
        // keeps the earliest occurrence.
#pragma unroll
        for (int j = 0; j < NPT; ++j) {
            float dx = __fsub_rn(px[j], lx);
            float dy = __fsub_rn(py[j], ly);
            float dz = __fsub_rn(pz[j], lz);
            float d  = __fadd_rn(__fadd_rn(__fmul_rn(dx, dx), __fmul_rn(dy, dy)),
                                 __fmul_rn(dz, dz));
            float nd = fminf(dist[j], d);
            dist[j] = nd;
            if (nd > bv) { bv = nd; bj = j; }
        }
        int bi = t + bj * THREADS;
        unsigned long long k =
            ((unsigned long long)__float_as_uint(bv) << 32) | (unsigned)(~bi);
        if (bv < 0.0f) k = 0;   // all-padded thread: must lose

        // wave (64-lane) butterfly max on the packed key
#pragma unroll
        for (int off = 1; off < 64; off <<= 1) {
            unsigned long long ok = __shfl_xor(k, off);
            if (ok > k) k = ok;
        }
        if ((t & 63) == 0) s_p[par][wid] = k;
        __syncthreads();
        // every thread max-scans the per-wave partials (uniform LDS reads)
        unsigned long long kmax = s_p[par][0];
#pragma unroll
        for (int w = 1; w < NWAVE; ++w) {
            unsigned long long v = s_p[par][w];
            if (v > kmax) kmax = v;
        }
        int sbi = __builtin_amdgcn_readfirstlane((int)~(unsigned)kmax);
        if (t == 0) idx_out[(size_t)b * m + it] = sbi;
        // winner coords: uniform (scalar) global load, L2-resident
        const float* __restrict__ wp = P + 3 * (size_t)sbi;
        lx = wp[0]; ly = wp[1]; lz = wp[2];
    }
}

// Gather sampled_C [batch,m,3] and sampled_F [batch,m,c] from the indices.
__global__ void gather_kernel(const float* __restrict__ C,
                              const float* __restrict__ F,
                              const int* __restrict__ idx,
                              float* __restrict__ outC,
                              float* __restrict__ outF,
                              int n_pts, int m, int c) {
    int pair = blockIdx.x;            // b*m + s
    int b = pair / m;
    int src = idx[pair];
    size_t srcbase = (size_t)b * n_pts + src;
    const float* sF = F + srcbase * (size_t)c;
    float* dF = outF + (size_t)pair * c;
    for (int i = threadIdx.x; i < c; i += blockDim.x) dF[i] = sF[i];
    if (threadIdx.x < 3)
        outC[(size_t)pair * 3 + threadIdx.x] = C[srcbase * 3 + threadIdx.x];
}

extern "C" void kernel_launch(void* const* d_in, const int* in_sizes, int n_in,
                              void* d_out, int out_size, void* d_ws, size_t ws_size,
                              hipStream_t stream) {
    const float* C = (const float*)d_in[0];
    const float* F = (const float*)d_in[1];

    int n_total = in_sizes[0] / 3;          // batch * n_pts
    int c       = in_sizes[1] / n_total;    // feature dim (128)
    int bm      = out_size / (3 + c);       // batch * m

    int batch = 8;
    if (bm % 2000 == 0) {
        int bb = bm / 2000;
        if (bb > 0 && n_total % bb == 0 && n_total / bb >= 2000) batch = bb;
    }
    int n_pts = n_total / batch;
    int m     = (n_pts < 2000) ? n_pts : 2000;

    int* idxbuf = (int*)d_ws;               // batch*m ints
    float* outC = (float*)d_out;
    float* outF = outC + (size_t)batch * m * 3;

    int npt = (n_pts + THREADS - 1) / THREADS;
#define LAUNCH_FPS(N) fps_kernel<N><<<batch, THREADS, 0, stream>>>(C, n_pts, m, idxbuf)
    if      (npt <= 4)  LAUNCH_FPS(4);
    else if (npt <= 8)  LAUNCH_FPS(8);
    else if (npt <= 12) LAUNCH_FPS(12);
    else if (npt <= 16) LAUNCH_FPS(16);
    else if (npt <= 20) LAUNCH_FPS(20);
    else if (npt <= 24) LAUNCH_FPS(24);
    else                LAUNCH_FPS(32);
#undef LAUNCH_FPS

    gather_kernel<<<batch * m, 128, 0, stream>>>(C, F, idxbuf, outC, outF,
                                                 n_pts, m, c);
}

// Round 5
// 4180.148 us; speedup vs baseline: 1.0199x; 1.0199x over previous
//
#include <hip/hip_runtime.h>
#include <hip/hip_bf16.h>

#define THREADS 1024
#define NWAVE (THREADS / 64)

typedef unsigned long long ull;

// One DPP argmax-combine round on a packed u64 key (hi=dist bits, lo=~idx).
// old=self for masked/out-of-bounds lanes -> no-op there. Max is
// commutative/associative so any reduce tree is exact; lo=~idx breaks
// value-ties toward the SMALLEST index (np.argmax first-occurrence).
template<int CTRL, int RM>
__device__ __forceinline__ ull kmax_dpp(ull k) {
    unsigned hi = (unsigned)(k >> 32), lo = (unsigned)k;
    unsigned hi2 = (unsigned)__builtin_amdgcn_update_dpp((int)hi, (int)hi, CTRL, RM, 0xf, false);
    unsigned lo2 = (unsigned)__builtin_amdgcn_update_dpp((int)lo, (int)lo, CTRL, RM, 0xf, false);
    ull k2 = ((ull)hi2 << 32) | lo2;
    return (k2 > k) ? k2 : k;
}

// Full 64-lane argmax: row_shr 1/2/4/8 (inclusive row reduce, lane15 of each
// 16-row = row total), row_bcast15 (rows 1,3), row_bcast31 (rows 2,3) ->
// lane 63 holds the wave argmax key.
__device__ __forceinline__ ull wave_kmax(ull k) {
    k = kmax_dpp<0x111, 0xf>(k);   // row_shr:1
    k = kmax_dpp<0x112, 0xf>(k);   // row_shr:2
    k = kmax_dpp<0x114, 0xf>(k);   // row_shr:4
    k = kmax_dpp<0x118, 0xf>(k);   // row_shr:8
    k = kmax_dpp<0x142, 0xa>(k);   // row_bcast:15 -> rows 1,3
    k = kmax_dpp<0x143, 0xc>(k);   // row_bcast:31 -> rows 2,3
    return k;
}

// One block per cloud, 16 waves (4/SIMD), per-thread state (80 floats at
// NPT=20) pinned to architectural VGPRs via empty asm each iteration.
// Per iteration (ONE barrier, parity-double-buffered partials):
//   dist pass + local argmax -> pack u64 key -> 6-round DPP wave argmax
//   (no LDS) -> lane63 writes partial -> barrier -> each wave reads
//   s_p[t&15], 4 DPP rounds across the 16-lane row -> readlane(15) ->
//   SGPR winner idx -> uniform scalar load of winner coords (L2-resident).
template<int NPT>
__global__ __launch_bounds__(THREADS)
__attribute__((amdgpu_waves_per_eu(4, 4)))
void fps_kernel(const float* __restrict__ C, int n_pts, int m,
                int* __restrict__ idx_out) {
    const int b = blockIdx.x;
    const int t = threadIdx.x;
    const float* __restrict__ P = C + (size_t)b * n_pts * 3;

    float px[NPT], py[NPT], pz[NPT], dist[NPT];
#pragma unroll
    for (int j = 0; j < NPT; ++j) {
        int g = t + j * THREADS;
        if (g < n_pts) {
            px[j] = P[3 * g + 0];
            py[j] = P[3 * g + 1];
            pz[j] = P[3 * g + 2];
            dist[j] = 1e10f;
        } else {
            px[j] = 0.f; py[j] = 0.f; pz[j] = 0.f;
            dist[j] = -1.0f;   // sentinel: never wins (real dists >= 0)
        }
    }

    __shared__ ull s_p[2][NWAVE];

    if (t == 0) idx_out[(size_t)b * m] = 0;   // first index is always 0

    // initial center = point 0 (uniform -> scalar load)
    float lx = P[0], ly = P[1], lz = P[2];

    const int wid = t >> 6;

    for (int it = 1; it < m; ++it) {
        const int par = it & 1;

        // Pin state to arch VGPRs: "v" is VGPR-only, so AGPR residence or
        // reload-remat would cost explicit copies here -> allocator keeps
        // the state resident in VGPRs (budget 128 = 4 waves/EU).
#pragma unroll
        for (int j = 0; j < NPT; ++j)
            asm volatile("" : "+v"(px[j]), "+v"(py[j]), "+v"(pz[j]), "+v"(dist[j]));

        float bv = -2.0f;
        int   bj = 0;
        // distance + min update + local argmax; ascending j with strict >
        // keeps the earliest occurrence.
#pragma unroll
        for (int j = 0; j < NPT; ++j) {
            float dx = __fsub_rn(px[j], lx);
            float dy = __fsub_rn(py[j], ly);
            float dz = __fsub_rn(pz[j], lz);
            float d  = __fadd_rn(__fadd_rn(__fmul_rn(dx, dx), __fmul_rn(dy, dy)),
                                 __fmul_rn(dz, dz));
            float nd = fminf(dist[j], d);
            dist[j] = nd;
            if (nd > bv) { bv = nd; bj = j; }
        }
        int bi = t + bj * THREADS;
        ull k = ((ull)__float_as_uint(bv) << 32) | (unsigned)(~bi);
        if (bv < 0.0f) k = 0;   // all-padded thread: must lose

        k = wave_kmax(k);                    // result in lane 63
        if ((t & 63) == 63) s_p[par][wid] = k;
        __syncthreads();

        // cross-wave: every lane reads one partial, 16-lane row DPP reduce
        ull kk = s_p[par][t & 15];
        kk = kmax_dpp<0x111, 0xf>(kk);
        kk = kmax_dpp<0x112, 0xf>(kk);
        kk = kmax_dpp<0x114, 0xf>(kk);
        kk = kmax_dpp<0x118, 0xf>(kk);       // lane 15 of each row = total
        int sbi = ~__builtin_amdgcn_readlane((int)(unsigned)kk, 15);

        if (t == 0) idx_out[(size_t)b * m + it] = sbi;
        // winner coords: uniform (scalar) global load, L2-resident
        const float* __restrict__ wp = P + 3 * (size_t)(unsigned)sbi;
        lx = wp[0]; ly = wp[1]; lz = wp[2];
    }
}

// Gather sampled_C [batch,m,3] and sampled_F [batch,m,c] from the indices.
__global__ void gather_kernel(const float* __restrict__ C,
                              const float* __restrict__ F,
                              const int* __restrict__ idx,
                              float* __restrict__ outC,
                              float* __restrict__ outF,
                              int n_pts, int m, int c) {
    int pair = blockIdx.x;            // b*m + s
    int b = pair / m;
    int src = idx[pair];
    size_t srcbase = (size_t)b * n_pts + src;
    const float* sF = F + srcbase * (size_t)c;
    float* dF = outF + (size_t)pair * c;
    for (int i = threadIdx.x; i < c; i += blockDim.x) dF[i] = sF[i];
    if (threadIdx.x < 3)
        outC[(size_t)pair * 3 + threadIdx.x] = C[srcbase * 3 + threadIdx.x];
}

extern "C" void kernel_launch(void* const* d_in, const int* in_sizes, int n_in,
                              void* d_out, int out_size, void* d_ws, size_t ws_size,
                              hipStream_t stream) {
    const float* C = (const float*)d_in[0];
    const float* F = (const float*)d_in[1];

    int n_total = in_sizes[0] / 3;          // batch * n_pts
    int c       = in_sizes[1] / n_total;    // feature dim (128)
    int bm      = out_size / (3 + c);       // batch * m

    int batch = 8;
    if (bm % 2000 == 0) {
        int bb = bm / 2000;
        if (bb > 0 && n_total % bb == 0 && n_total / bb >= 2000) batch = bb;
    }
    int n_pts = n_total / batch;
    int m     = (n_pts < 2000) ? n_pts : 2000;

    int* idxbuf = (int*)d_ws;               // batch*m ints
    float* outC = (float*)d_out;
    float* outF = outC + (size_t)batch * m * 3;

    int npt = (n_pts + THREADS - 1) / THREADS;
#define LAUNCH_FPS(N) fps_kernel<N><<<batch, THREADS, 0, stream>>>(C, n_pts, m, idxbuf)
    if      (npt <= 4)  LAUNCH_FPS(4);
    else if (npt <= 8)  LAUNCH_FPS(8);
    else if (npt <= 12) LAUNCH_FPS(12);
    else if (npt <= 16) LAUNCH_FPS(16);
    else if (npt <= 20) LAUNCH_FPS(20);
    else if (npt <= 24) LAUNCH_FPS(24);
    else                LAUNCH_FPS(32);
#undef LAUNCH_FPS

    gather_kernel<<<batch * m, 128, 0, stream>>>(C, F, idxbuf, outC, outF,
                                                 n_pts, m, c);
}

// Round 6
// 3861.301 us; speedup vs baseline: 1.1041x; 1.0826x over previous
//
#include <hip/hip_runtime.h>
#include <hip/hip_bf16.h>

#define THREADS 1024
#define NWAVE (THREADS / 64)

typedef unsigned long long ull;

// f32 max with DPP-shifted partner; old=self so masked lanes are no-ops.
// GCNDPPCombine folds the dpp-mov into v_max_f32 (single instruction).
template<int CTRL, int RM>
__device__ __forceinline__ float fmax_dpp(float v) {
    int s = __builtin_amdgcn_update_dpp(__float_as_int(v), __float_as_int(v),
                                        CTRL, RM, 0xf, false);
    return fmaxf(v, __int_as_float(s));
}

// u64 (value,~idx) key max via DPP, as validated in round 5.
template<int CTRL, int RM>
__device__ __forceinline__ ull kmax_dpp(ull k) {
    unsigned hi = (unsigned)(k >> 32), lo = (unsigned)k;
    unsigned hi2 = (unsigned)__builtin_amdgcn_update_dpp((int)hi, (int)hi, CTRL, RM, 0xf, false);
    unsigned lo2 = (unsigned)__builtin_amdgcn_update_dpp((int)lo, (int)lo, CTRL, RM, 0xf, false);
    ull k2 = ((ull)hi2 << 32) | lo2;
    return (k2 > k) ? k2 : k;
}

// One block per cloud, 16 waves (4/SIMD). Per iteration (ONE barrier):
//  1. dist pass, VALue-only max tracking (10 VALU/point, dual accumulators)
//  2. wave f32 max: 6 DPP rounds -> readlane(63) -> smax in SGPR
//  3. index recovery on the SCALAR pipe: NPT ballots (1 VALU each) ->
//     first nonzero mask (SALU selects) -> ctzll -> wave argmax index.
//     Exact: fmax returns one of its inputs bit-exactly, and index ranges
//     per j are disjoint ascending, so first-j/first-lane = smallest index
//     (np.argmax first-occurrence).
//  4. wave leader packs (maxbits<<32)|~idx in SGPRs, writes LDS partial
//     (parity double-buffered); barrier; 16-partial u64 row-DPP max;
//     readlane -> winner idx; uniform scalar load of winner coords.
template<int NPT>
__global__ __launch_bounds__(THREADS)
__attribute__((amdgpu_waves_per_eu(4, 4)))
void fps_kernel(const float* __restrict__ C, int n_pts, int m,
                int* __restrict__ idx_out) {
    const int b = blockIdx.x;
    const int t = threadIdx.x;
    const float* __restrict__ P = C + (size_t)b * n_pts * 3;

    float px[NPT], py[NPT], pz[NPT], dist[NPT];
#pragma unroll
    for (int j = 0; j < NPT; ++j) {
        int g = t + j * THREADS;
        if (g < n_pts) {
            px[j] = P[3 * g + 0];
            py[j] = P[3 * g + 1];
            pz[j] = P[3 * g + 2];
            dist[j] = 1e10f;
        } else {
            px[j] = 0.f; py[j] = 0.f; pz[j] = 0.f;
            dist[j] = -1.0f;   // sentinel: never equals smax (>= 0)
        }
    }

    __shared__ ull s_p[2][NWAVE];

    if (t == 0) idx_out[(size_t)b * m] = 0;   // first index is always 0

    // initial center = point 0 (uniform -> scalar load)
    float lx = P[0], ly = P[1], lz = P[2];

    const int wid = t >> 6;

    for (int it = 1; it < m; ++it) {
        const int par = it & 1;

        // 1. distance + min update, value-only max (two accumulators)
        float vmaxA = -2.0f, vmaxB = -2.0f;
#pragma unroll
        for (int j = 0; j < NPT; ++j) {
            float dx = __fsub_rn(px[j], lx);
            float dy = __fsub_rn(py[j], ly);
            float dz = __fsub_rn(pz[j], lz);
            float d  = __fadd_rn(__fadd_rn(__fmul_rn(dx, dx), __fmul_rn(dy, dy)),
                                 __fmul_rn(dz, dz));
            float nd = fminf(dist[j], d);
            dist[j] = nd;
            if (j & 1) vmaxB = fmaxf(vmaxB, nd);
            else       vmaxA = fmaxf(vmaxA, nd);
        }
        float v = fmaxf(vmaxA, vmaxB);

        // 2. wave max (value only), single-instr DPP rounds
        v = fmax_dpp<0x111, 0xf>(v);   // row_shr:1
        v = fmax_dpp<0x112, 0xf>(v);   // row_shr:2
        v = fmax_dpp<0x114, 0xf>(v);   // row_shr:4
        v = fmax_dpp<0x118, 0xf>(v);   // row_shr:8
        v = fmax_dpp<0x142, 0xa>(v);   // row_bcast:15 -> rows 1,3
        v = fmax_dpp<0x143, 0xc>(v);   // row_bcast:31 -> rows 2,3
        float smax = __int_as_float(
            __builtin_amdgcn_readlane(__float_as_int(v), 63));  // SGPR

        // 3. wave argmax index: ballots + scalar scan (SALU pipe)
        ull bestmask = 0;
        int bj = 0;
#pragma unroll
        for (int j = 0; j < NPT; ++j) {
            ull mj = __ballot(dist[j] == smax);
            bool take = (bestmask == 0);   // uniform -> scalar select
            if (take) { bestmask = mj; bj = j; }
        }
        int lane = (int)__builtin_ctzll(bestmask);
        int widx = wid * 64 + lane + bj * THREADS;

        // 4. pack key in SGPRs, leader writes partial, barrier, reduce
        ull key = ((ull)__float_as_uint(smax) << 32) | (unsigned)(~widx);
        if ((t & 63) == 0) s_p[par][wid] = key;
        __syncthreads();

        ull kk = s_p[par][t & 15];
        kk = kmax_dpp<0x111, 0xf>(kk);
        kk = kmax_dpp<0x112, 0xf>(kk);
        kk = kmax_dpp<0x114, 0xf>(kk);
        kk = kmax_dpp<0x118, 0xf>(kk);       // lane 15 of each row = total
        int sbi = ~__builtin_amdgcn_readlane((int)(unsigned)kk, 15);

        if (t == 0) idx_out[(size_t)b * m + it] = sbi;
        // winner coords: uniform (scalar) global load, L2-resident
        const float* __restrict__ wp = P + 3 * (size_t)(unsigned)sbi;
        lx = wp[0]; ly = wp[1]; lz = wp[2];
    }
}

// Gather sampled_C [batch,m,3] and sampled_F [batch,m,c] from the indices.
__global__ void gather_kernel(const float* __restrict__ C,
                              const float* __restrict__ F,
                              const int* __restrict__ idx,
                              float* __restrict__ outC,
                              float* __restrict__ outF,
                              int n_pts, int m, int c) {
    int pair = blockIdx.x;            // b*m + s
    int b = pair / m;
    int src = idx[pair];
    size_t srcbase = (size_t)b * n_pts + src;
    const float* sF = F + srcbase * (size_t)c;
    float* dF = outF + (size_t)pair * c;
    for (int i = threadIdx.x; i < c; i += blockDim.x) dF[i] = sF[i];
    if (threadIdx.x < 3)
        outC[(size_t)pair * 3 + threadIdx.x] = C[srcbase * 3 + threadIdx.x];
}

extern "C" void kernel_launch(void* const* d_in, const int* in_sizes, int n_in,
                              void* d_out, int out_size, void* d_ws, size_t ws_size,
                              hipStream_t stream) {
    const float* C = (const float*)d_in[0];
    const float* F = (const float*)d_in[1];

    int n_total = in_sizes[0] / 3;          // batch * n_pts
    int c       = in_sizes[1] / n_total;    // feature dim (128)
    int bm      = out_size / (3 + c);       // batch * m

    int batch = 8;
    if (bm % 2000 == 0) {
        int bb = bm / 2000;
        if (bb > 0 && n_total % bb == 0 && n_total / bb >= 2000) batch = bb;
    }
    int n_pts = n_total / batch;
    int m     = (n_pts < 2000) ? n_pts : 2000;

    int* idxbuf = (int*)d_ws;               // batch*m ints
    float* outC = (float*)d_out;
    float* outF = outC + (size_t)batch * m * 3;

    int npt = (n_pts + THREADS - 1) / THREADS;
#define LAUNCH_FPS(N) fps_kernel<N><<<batch, THREADS, 0, stream>>>(C, n_pts, m, idxbuf)
    if      (npt <= 4)  LAUNCH_FPS(4);
    else if (npt <= 8)  LAUNCH_FPS(8);
    else if (npt <= 12) LAUNCH_FPS(12);
    else if (npt <= 16) LAUNCH_FPS(16);
    else if (npt <= 20) LAUNCH_FPS(20);
    else if (npt <= 24) LAUNCH_FPS(24);
    else                LAUNCH_FPS(32);
#undef LAUNCH_FPS

    gather_kernel<<<batch * m, 128, 0, stream>>>(C, F, idxbuf, outC, outF,
                                                 n_pts, m, c);
}